// Round 8
// baseline (128.962 us; speedup 1.0000x reference)
//
#include <hip/hip_runtime.h>
#include <hip/hip_bf16.h>

typedef __attribute__((ext_vector_type(8))) short bf16x8;
typedef __attribute__((ext_vector_type(4))) float f32x4;

#define U_LD 2176      // padded K (multiple of 64)
#define K_REAL 2145    // 33*65
#define NKT 34         // 2176/64
#define KSPLIT 17      // K-steps per block (split-K=2)
#define DIM0 33
#define DIM1 33
#define DIM2 65
#define NROW 2048
#define OO 128

__device__ __forceinline__ unsigned short f2bf(float f) {
  union { float f; unsigned u; } v; v.f = f;
  unsigned r = v.u + 0x7fffu + ((v.u >> 16) & 1u);   // round-to-nearest-even
  return (unsigned short)(r >> 16);
}

#define GLOAD_LDS16(SRC, DST) \
  __builtin_amdgcn_global_load_lds((const __attribute__((address_space(1))) void*)(SRC), \
                                   (__attribute__((address_space(3))) void*)(DST), 16, 0, 0)

// ---- U[n][k] = bf16( x1[n,b] * x2[n,c] ),  k = b*65+c, zero-padded to 2176 ----
__global__ __launch_bounds__(256) void prep_u_kernel(const float* __restrict__ x1,
                                                     const float* __restrict__ x2,
                                                     ushort* __restrict__ U) {
  __shared__ float s1[DIM1], s2[DIM2];
  int n = blockIdx.x;
  int tid = threadIdx.x;
  if (tid < DIM1) s1[tid] = x1[n * DIM1 + tid];
  int t2 = tid - DIM1;
  if (t2 >= 0 && t2 < DIM2) s2[t2] = x2[n * DIM2 + t2];
  __syncthreads();
  for (int k8 = tid; k8 < U_LD / 8; k8 += 256) {
    union { ushort us[8]; uint4 v; } pk;
#pragma unroll
    for (int j = 0; j < 8; ++j) {
      int k = k8 * 8 + j;
      float val = 0.f;
      if (k < K_REAL) { int b = k / DIM2; int c = k - b * DIM2; val = s1[b] * s2[c]; }
      pk.us[j] = f2bf(val);
    }
    *(uint4*)&U[(size_t)n * U_LD + k8 * 8] = pk.v;
  }
}

// ---- Wt[a][o][k] = bf16( W[a,b,c,o] ), k = b*65+c, zero-padded ----
__global__ __launch_bounds__(256) void prep_wt_kernel(const float* __restrict__ W,
                                                      ushort* __restrict__ Wt) {
  __shared__ ushort s[64][130];   // [k][o], pad to 130 to spread banks
  int a = blockIdx.y;
  int k0 = blockIdx.x * 64;       // 34 slabs of 64 k
  int tid = threadIdx.x;
  for (int idx = tid; idx < 64 * 32; idx += 256) {
    int kk = idx >> 5;
    int og = (idx & 31) * 4;
    int k = k0 + kk;
    float4 v = make_float4(0.f, 0.f, 0.f, 0.f);
    if (k < K_REAL) {
      int b = k / DIM2; int c = k - b * DIM2;
      v = *(const float4*)&W[(((size_t)a * DIM1 + b) * DIM2 + c) * OO + og];
    }
    s[kk][og]     = f2bf(v.x);
    s[kk][og + 1] = f2bf(v.y);
    s[kk][og + 2] = f2bf(v.z);
    s[kk][og + 3] = f2bf(v.w);
  }
  __syncthreads();
  int o  = tid >> 1;
  int kh = (tid & 1) * 32;
  union { ushort us[32]; uint4 v[4]; } pk;
#pragma unroll
  for (int j = 0; j < 32; ++j) pk.us[j] = s[kh + j][o];
  uint4* dst = (uint4*)&Wt[((size_t)a * OO + o) * U_LD + k0 + kh];
#pragma unroll
  for (int q = 0; q < 4; ++q) dst[q] = pk.v[q];
}

// ---- main GEMM: 128x128 tile, one (a, K-half) per block, 16x16x32 MFMA,
//      4 waves of 64x64. Counted-vmcnt double-buffer (R4 pipeline). ----
__global__ __launch_bounds__(256, 2) void gemm_kernel(const ushort* __restrict__ U,
                                                      const ushort* __restrict__ Wt,
                                                      const float* __restrict__ x0,
                                                      float* __restrict__ out) {
  // per buffer: A [128 rows][64 k] = 16KB (ushort 0..8191), B [128 o][64 k] = 16KB (8192..16383)
  __shared__ ushort lds[2][16384];   // 64 KB -> 2 blocks/CU

  int tid = threadIdx.x;
  int lane = tid & 63;
  int w = tid >> 6;
  int wr = w >> 1, wc = w & 1;       // wave tile: rows wr*64.., cols wc*64..

  // XCD-aware bijective swizzle: 1056 blocks, 132 per XCD, a-major within XCD.
  int orig = (int)blockIdx.x;
  int logical = (orig & 7) * 132 + (orig >> 3);
  int a = logical >> 5;              // 0..32
  int rem = logical & 31;
  int m = rem >> 1;                  // 0..15
  int h = rem & 1;                   // K-half
  int n0 = m * 128;
  int kk0 = h * KSPLIT * 64;

  int kblk = lane >> 4;              // 0..3
  int r15 = lane & 15;
  int swz = lane & 7;                // == row&7 for all fragment rows this lane touches

  f32x4 acc[4][4];
#pragma unroll
  for (int mi = 0; mi < 4; ++mi)
#pragma unroll
    for (int ni = 0; ni < 4; ++ni)
      acc[mi][ni] = (f32x4){0.f, 0.f, 0.f, 0.f};

  const ushort* WtA = Wt + (size_t)a * OO * U_LD;

  // --- per-thread staging: 8 chunks (4 A + 4 B), pointer-bumped +64 ushorts/step ---
  // chunk c in 0..1023: row = c>>3, slot = c&7; LDS dest linear c*16 bytes;
  // global source granule = slot ^ (row&7)  (involution, undone on read side)
  const ushort* pA[4]; const ushort* pB[4];
  int dA[4], dB[4];
#pragma unroll
  for (int i = 0; i < 4; ++i) {
    int c = i * 256 + tid;
    int row = c >> 3;
    int ss = (c & 7) ^ (row & 7);
    pA[i] = U + (size_t)(n0 + row) * U_LD + kk0 + ss * 8;
    dA[i] = c * 8;
    pB[i] = WtA + (size_t)row * U_LD + kk0 + ss * 8;
    dB[i] = 8192 + c * 8;
  }

  auto STAGE = [&](ushort* Lb) {
#pragma unroll
    for (int i = 0; i < 4; ++i) { GLOAD_LDS16(pA[i], Lb + dA[i]); pA[i] += 64; }
#pragma unroll
    for (int i = 0; i < 4; ++i) { GLOAD_LDS16(pB[i], Lb + dB[i]); pB[i] += 64; }
  };

  auto COMPUTE = [&](const ushort* Lb) {
    const char* base = (const char*)Lb;
#pragma unroll
    for (int ks = 0; ks < 2; ++ks) {
      bf16x8 af[4], bfr[4];
#pragma unroll
      for (int mi = 0; mi < 4; ++mi) {
        int off = (wr * 64 + mi * 16 + r15) * 128 + ((((ks * 4) + kblk) ^ swz) << 4);
        af[mi] = *(const bf16x8*)(base + off);
      }
#pragma unroll
      for (int ni = 0; ni < 4; ++ni) {
        int off = 16384 + (wc * 64 + ni * 16 + r15) * 128 + ((((ks * 4) + kblk) ^ swz) << 4);
        bfr[ni] = *(const bf16x8*)(base + off);
      }
      __builtin_amdgcn_s_setprio(1);
#pragma unroll
      for (int mi = 0; mi < 4; ++mi)
#pragma unroll
        for (int ni = 0; ni < 4; ++ni)
          acc[mi][ni] = __builtin_amdgcn_mfma_f32_16x16x32_bf16(af[mi], bfr[ni], acc[mi][ni], 0, 0, 0);
      __builtin_amdgcn_s_setprio(0);
    }
  };

  // prologue: tiles 0,1 in flight (16 loads); wait tile 0 (16-8=8 oldest)
  STAGE(&lds[0][0]);
  STAGE(&lds[1][0]);
  asm volatile("s_waitcnt vmcnt(8)" ::: "memory");
  __builtin_amdgcn_s_barrier();

  // steady state over 17 tiles: 2x unroll, compile-time buffer index.
  // it=0..6 computes t=0..13, stages t=2..15.
  for (int it = 0; it < 7; ++it) {
    COMPUTE(&lds[0][0]);
    __builtin_amdgcn_s_barrier();            // readers done with b0
    STAGE(&lds[0][0]);                       // tile 2it+2 -> b0 (16 in flight)
    asm volatile("s_waitcnt vmcnt(8)" ::: "memory");   // b1's tile landed
    __builtin_amdgcn_s_barrier();
    COMPUTE(&lds[1][0]);
    __builtin_amdgcn_s_barrier();
    STAGE(&lds[1][0]);                       // tile 2it+3 -> b1
    asm volatile("s_waitcnt vmcnt(8)" ::: "memory");   // b0's tile landed
    __builtin_amdgcn_s_barrier();
  }
  // t=14 (b0, landed); stage t=16 -> b0; t=15 lands
  COMPUTE(&lds[0][0]);
  __builtin_amdgcn_s_barrier();
  STAGE(&lds[0][0]);
  asm volatile("s_waitcnt vmcnt(8)" ::: "memory");
  __builtin_amdgcn_s_barrier();
  // t=15 (b1)
  COMPUTE(&lds[1][0]);
  asm volatile("s_waitcnt vmcnt(0)" ::: "memory");   // own t=16 loads done
  __builtin_amdgcn_s_barrier();                      // => all waves' loads done
  // t=16 (b0)
  COMPUTE(&lds[0][0]);

  // epilogue: scale by x0[row, a], atomic-accumulate into out
  int jrow = (lane >> 4) * 4;
#pragma unroll
  for (int mi = 0; mi < 4; ++mi) {
#pragma unroll
    for (int j = 0; j < 4; ++j) {
      int row = n0 + wr * 64 + mi * 16 + jrow + j;
      float s = x0[(size_t)row * DIM0 + a];
#pragma unroll
      for (int ni = 0; ni < 4; ++ni) {
        int col = wc * 64 + ni * 16 + r15;
        atomicAdd(&out[(size_t)row * OO + col], acc[mi][ni][j] * s);
      }
    }
  }
}

// ---- bias + relu, in place on d_out ----
__global__ __launch_bounds__(256) void relu_kernel(float* __restrict__ out,
                                                   const float* __restrict__ bias) {
  int i = blockIdx.x * 256 + threadIdx.x;
  out[i] = fmaxf(out[i] + bias[i & (OO - 1)], 0.f);
}

extern "C" void kernel_launch(void* const* d_in, const int* in_sizes, int n_in,
                              void* d_out, int out_size, void* d_ws, size_t ws_size,
                              hipStream_t stream) {
  const float* x0   = (const float*)d_in[0];
  const float* x1   = (const float*)d_in[1];
  const float* x2   = (const float*)d_in[2];
  const float* W    = (const float*)d_in[3];
  const float* bias = (const float*)d_in[4];
  float* out = (float*)d_out;

  ushort* U  = (ushort*)d_ws;                                   // 2048*2176*2 = 8,912,896 B
  ushort* Wt = (ushort*)((char*)d_ws + (size_t)8912896);        // 33*128*2176*2 = 18,382,848 B

  hipMemsetAsync(d_out, 0, (size_t)NROW * OO * sizeof(float), stream);
  prep_u_kernel<<<NROW, 256, 0, stream>>>(x1, x2, U);
  prep_wt_kernel<<<dim3(34, 33), 256, 0, stream>>>(W, Wt);
  gemm_kernel<<<1056, 256, 0, stream>>>(U, Wt, x0, out);
  relu_kernel<<<(NROW * OO) / 256, 256, 0, stream>>>(out, bias);
}

// Round 10
// 110.812 us; speedup vs baseline: 1.1638x; 1.1638x over previous
//
#include <hip/hip_runtime.h>
#include <hip/hip_bf16.h>

typedef __attribute__((ext_vector_type(8))) short bf16x8;
typedef __attribute__((ext_vector_type(4))) float f32x4;

#define U_LD 2176      // padded K (multiple of 64)
#define K_REAL 2145    // 33*65
#define NKT 34         // 2176/64
#define DIM0 33
#define DIM1 33
#define DIM2 65
#define NROW 2048
#define OO 128

__device__ __forceinline__ unsigned short f2bf(float f) {
  union { float f; unsigned u; } v; v.f = f;
  unsigned r = v.u + 0x7fffu + ((v.u >> 16) & 1u);   // round-to-nearest-even
  return (unsigned short)(r >> 16);
}

#define GLOAD_LDS16(SRC, DST) \
  __builtin_amdgcn_global_load_lds((const __attribute__((address_space(1))) void*)(SRC), \
                                   (__attribute__((address_space(3))) void*)(DST), 16, 0, 0)

// ---- U[n][k] = bf16( x1[n,b] * x2[n,c] ),  k = b*65+c, zero-padded to 2176 ----
__global__ __launch_bounds__(256) void prep_u_kernel(const float* __restrict__ x1,
                                                     const float* __restrict__ x2,
                                                     ushort* __restrict__ U) {
  __shared__ float s1[DIM1], s2[DIM2];
  int n = blockIdx.x;
  int tid = threadIdx.x;
  if (tid < DIM1) s1[tid] = x1[n * DIM1 + tid];
  int t2 = tid - DIM1;
  if (t2 >= 0 && t2 < DIM2) s2[t2] = x2[n * DIM2 + t2];
  __syncthreads();
  for (int k8 = tid; k8 < U_LD / 8; k8 += 256) {
    union { ushort us[8]; uint4 v; } pk;
#pragma unroll
    for (int j = 0; j < 8; ++j) {
      int k = k8 * 8 + j;
      float val = 0.f;
      if (k < K_REAL) { int b = k / DIM2; int c = k - b * DIM2; val = s1[b] * s2[c]; }
      pk.us[j] = f2bf(val);
    }
    *(uint4*)&U[(size_t)n * U_LD + k8 * 8] = pk.v;
  }
}

// ---- Wt[a][o][k] = bf16( W[a,b,c,o] ), k = b*65+c, zero-padded ----
__global__ __launch_bounds__(256) void prep_wt_kernel(const float* __restrict__ W,
                                                      ushort* __restrict__ Wt) {
  __shared__ ushort s[64][130];   // [k][o], pad to 130 to spread banks
  int a = blockIdx.y;
  int k0 = blockIdx.x * 64;       // 34 slabs of 64 k
  int tid = threadIdx.x;
  for (int idx = tid; idx < 64 * 32; idx += 256) {
    int kk = idx >> 5;
    int og = (idx & 31) * 4;
    int k = k0 + kk;
    float4 v = make_float4(0.f, 0.f, 0.f, 0.f);
    if (k < K_REAL) {
      int b = k / DIM2; int c = k - b * DIM2;
      v = *(const float4*)&W[(((size_t)a * DIM1 + b) * DIM2 + c) * OO + og];
    }
    s[kk][og]     = f2bf(v.x);
    s[kk][og + 1] = f2bf(v.y);
    s[kk][og + 2] = f2bf(v.z);
    s[kk][og + 3] = f2bf(v.w);
  }
  __syncthreads();
  int o  = tid >> 1;
  int kh = (tid & 1) * 32;
  union { ushort us[32]; uint4 v[4]; } pk;
#pragma unroll
  for (int j = 0; j < 32; ++j) pk.us[j] = s[kh + j][o];
  uint4* dst = (uint4*)&Wt[((size_t)a * OO + o) * U_LD + k0 + kh];
#pragma unroll
  for (int q = 0; q < 4; ++q) dst[q] = pk.v[q];
}

// ---- main GEMM: 128x128 tile, one a per block, 8 waves (4x2 of 32x64),
//      16x16x32 MFMA, R4 counted-vmcnt double-buffer. 64KB LDS -> 2 blocks/CU
//      -> 16 waves/CU (4/SIMD). ----
__global__ __launch_bounds__(512, 4) void gemm_kernel(const ushort* __restrict__ U,
                                                      const ushort* __restrict__ Wt,
                                                      const float* __restrict__ x0,
                                                      float* __restrict__ out) {
  // per buffer: A [128 rows][64 k] = 16KB (ushort 0..8191), B [128 o][64 k] = 16KB (8192..16383)
  __shared__ ushort lds[2][16384];   // 64 KB

  int tid = threadIdx.x;
  int lane = tid & 63;
  int w = tid >> 6;                  // 0..7
  int wr = w >> 1, wc = w & 1;       // wave tile: rows wr*32.., cols wc*64..

  // XCD-aware bijective swizzle: 528 blocks, 66 per XCD, a-major within XCD.
  int orig = (int)blockIdx.x;
  int logical = (orig & 7) * 66 + (orig >> 3);
  int a = logical >> 4;              // 0..32
  int m = logical & 15;              // 0..15
  int n0 = m * 128;

  int kblk = lane >> 4;              // 0..3
  int r15 = lane & 15;
  int swz = lane & 7;                // == row&7 for all fragment rows this lane touches

  f32x4 acc[2][4];
#pragma unroll
  for (int mi = 0; mi < 2; ++mi)
#pragma unroll
    for (int ni = 0; ni < 4; ++ni)
      acc[mi][ni] = (f32x4){0.f, 0.f, 0.f, 0.f};

  const ushort* WtA = Wt + (size_t)a * OO * U_LD;

  // --- per-thread staging: 4 chunks (2 A + 2 B), pointer-bumped +64 ushorts/step ---
  // chunk c in 0..1023: row = c>>3, slot = c&7; LDS dest linear c*16 bytes;
  // global source granule = slot ^ (row&7)  (involution, undone on read side)
  const ushort* pA[2]; const ushort* pB[2];
  int dA[2], dB[2];
#pragma unroll
  for (int i = 0; i < 2; ++i) {
    int c = i * 512 + tid;
    int row = c >> 3;
    int ss = (c & 7) ^ (row & 7);
    pA[i] = U + (size_t)(n0 + row) * U_LD + ss * 8;
    dA[i] = c * 8;
    pB[i] = WtA + (size_t)row * U_LD + ss * 8;
    dB[i] = 8192 + c * 8;
  }

  auto STAGE = [&](ushort* Lb) {
#pragma unroll
    for (int i = 0; i < 2; ++i) { GLOAD_LDS16(pA[i], Lb + dA[i]); pA[i] += 64; }
#pragma unroll
    for (int i = 0; i < 2; ++i) { GLOAD_LDS16(pB[i], Lb + dB[i]); pB[i] += 64; }
  };

  auto COMPUTE = [&](const ushort* Lb) {
    const char* base = (const char*)Lb;
#pragma unroll
    for (int ks = 0; ks < 2; ++ks) {
      bf16x8 af[2], bfr[4];
#pragma unroll
      for (int mi = 0; mi < 2; ++mi) {
        int off = (wr * 32 + mi * 16 + r15) * 128 + ((((ks * 4) + kblk) ^ swz) << 4);
        af[mi] = *(const bf16x8*)(base + off);
      }
#pragma unroll
      for (int ni = 0; ni < 4; ++ni) {
        // B region starts at ushort 8192 = BYTE 16384 (R9 bug: was 32768)
        int off = 16384 + (wc * 64 + ni * 16 + r15) * 128 + ((((ks * 4) + kblk) ^ swz) << 4);
        bfr[ni] = *(const bf16x8*)(base + off);
      }
      __builtin_amdgcn_s_setprio(1);
#pragma unroll
      for (int mi = 0; mi < 2; ++mi)
#pragma unroll
        for (int ni = 0; ni < 4; ++ni)
          acc[mi][ni] = __builtin_amdgcn_mfma_f32_16x16x32_bf16(af[mi], bfr[ni], acc[mi][ni], 0, 0, 0);
      __builtin_amdgcn_s_setprio(0);
    }
  };

  // prologue: tiles 0,1 in flight (8 loads/thread); wait tile 0 (keep 4 newest)
  STAGE(&lds[0][0]);
  STAGE(&lds[1][0]);
  asm volatile("s_waitcnt vmcnt(4)" ::: "memory");
  __builtin_amdgcn_s_barrier();

  // steady state: 34 tiles, 2x unroll for compile-time buffer index.
  for (int it = 0; it < 16; ++it) {
    COMPUTE(&lds[0][0]);
    __builtin_amdgcn_s_barrier();            // readers done with b0
    STAGE(&lds[0][0]);                       // tile 2it+2 -> b0 (8/thread in flight)
    asm volatile("s_waitcnt vmcnt(4)" ::: "memory");   // b1's tile landed
    __builtin_amdgcn_s_barrier();
    COMPUTE(&lds[1][0]);
    __builtin_amdgcn_s_barrier();
    STAGE(&lds[1][0]);                       // tile 2it+3 -> b1
    asm volatile("s_waitcnt vmcnt(4)" ::: "memory");   // b0's tile landed
    __builtin_amdgcn_s_barrier();
  }
  // tiles 32 (b0, landed) and 33 (b1, in flight)
  COMPUTE(&lds[0][0]);
  asm volatile("s_waitcnt vmcnt(0)" ::: "memory");
  __builtin_amdgcn_s_barrier();
  COMPUTE(&lds[1][0]);

  // epilogue: scale by x0[row, a], atomic-accumulate into out
  int jrow = (lane >> 4) * 4;
#pragma unroll
  for (int mi = 0; mi < 2; ++mi) {
#pragma unroll
    for (int j = 0; j < 4; ++j) {
      int row = n0 + wr * 32 + mi * 16 + jrow + j;
      float s = x0[(size_t)row * DIM0 + a];
#pragma unroll
      for (int ni = 0; ni < 4; ++ni) {
        int col = wc * 64 + ni * 16 + r15;
        atomicAdd(&out[(size_t)row * OO + col], acc[mi][ni][j] * s);
      }
    }
  }
}

// ---- bias + relu, in place on d_out ----
__global__ __launch_bounds__(256) void relu_kernel(float* __restrict__ out,
                                                   const float* __restrict__ bias) {
  int i = blockIdx.x * 256 + threadIdx.x;
  out[i] = fmaxf(out[i] + bias[i & (OO - 1)], 0.f);
}

extern "C" void kernel_launch(void* const* d_in, const int* in_sizes, int n_in,
                              void* d_out, int out_size, void* d_ws, size_t ws_size,
                              hipStream_t stream) {
  const float* x0   = (const float*)d_in[0];
  const float* x1   = (const float*)d_in[1];
  const float* x2   = (const float*)d_in[2];
  const float* W    = (const float*)d_in[3];
  const float* bias = (const float*)d_in[4];
  float* out = (float*)d_out;

  ushort* U  = (ushort*)d_ws;                                   // 2048*2176*2 = 8,912,896 B
  ushort* Wt = (ushort*)((char*)d_ws + (size_t)8912896);        // 33*128*2176*2 = 18,382,848 B

  hipMemsetAsync(d_out, 0, (size_t)NROW * OO * sizeof(float), stream);
  prep_u_kernel<<<NROW, 256, 0, stream>>>(x1, x2, U);
  prep_wt_kernel<<<dim3(34, 33), 256, 0, stream>>>(W, Wt);
  gemm_kernel<<<528, 512, 0, stream>>>(U, Wt, x0, out);
  relu_kernel<<<(NROW * OO) / 256, 256, 0, stream>>>(out, bias);
}

// Round 11
// 110.537 us; speedup vs baseline: 1.1667x; 1.0025x over previous
//
#include <hip/hip_runtime.h>
#include <hip/hip_bf16.h>

typedef __attribute__((ext_vector_type(8))) short bf16x8;
typedef __attribute__((ext_vector_type(4))) float f32x4;

#define U_LD 2176      // padded K (multiple of 64)
#define K_REAL 2145    // 33*65
#define NKT 34         // 2176/64
#define DIM0 33
#define DIM1 33
#define DIM2 65
#define NROW 2048
#define OO 128

__device__ __forceinline__ unsigned short f2bf(float f) {
  union { float f; unsigned u; } v; v.f = f;
  unsigned r = v.u + 0x7fffu + ((v.u >> 16) & 1u);   // round-to-nearest-even
  return (unsigned short)(r >> 16);
}

#define GLOAD_LDS16(SRC, DST) \
  __builtin_amdgcn_global_load_lds((const __attribute__((address_space(1))) void*)(SRC), \
                                   (__attribute__((address_space(3))) void*)(DST), 16, 0, 0)

// ---- merged prep: blocks 0..1121 convert W -> Wt[a][o][k] (bf16, k-contig);
//      blocks 1122..3169 build U[n][k] = bf16(x1[n,b]*x2[n,c]). Merging lets
//      the two halves overlap on the CU array (they serialized before). ----
__global__ __launch_bounds__(256) void prep_kernel(const float* __restrict__ x1,
                                                   const float* __restrict__ x2,
                                                   const float* __restrict__ W,
                                                   ushort* __restrict__ U,
                                                   ushort* __restrict__ Wt) {
  __shared__ ushort s[64][130];   // [k][o], pad to 130 to spread banks
  int bx = (int)blockIdx.x;
  int tid = threadIdx.x;
  if (bx < 34 * 33) {
    // ---- Wt slab: a = bx%33, k0 = (bx/33)*64 ----
    int a = bx % 33;
    int k0 = (bx / 33) * 64;
    for (int idx = tid; idx < 64 * 32; idx += 256) {
      int kk = idx >> 5;
      int og = (idx & 31) * 4;
      int k = k0 + kk;
      float4 v = make_float4(0.f, 0.f, 0.f, 0.f);
      if (k < K_REAL) {
        int b = k / DIM2; int c = k - b * DIM2;
        v = *(const float4*)&W[(((size_t)a * DIM1 + b) * DIM2 + c) * OO + og];
      }
      s[kk][og]     = f2bf(v.x);
      s[kk][og + 1] = f2bf(v.y);
      s[kk][og + 2] = f2bf(v.z);
      s[kk][og + 3] = f2bf(v.w);
    }
    __syncthreads();
    int o  = tid >> 1;
    int kh = (tid & 1) * 32;
    union { ushort us[32]; uint4 v[4]; } pk;
#pragma unroll
    for (int j = 0; j < 32; ++j) pk.us[j] = s[kh + j][o];
    uint4* dst = (uint4*)&Wt[((size_t)a * OO + o) * U_LD + k0 + kh];
#pragma unroll
    for (int q = 0; q < 4; ++q) dst[q] = pk.v[q];
  } else {
    // ---- U row: n = bx - 1122 ----
    int n = bx - 34 * 33;
    float* s1 = (float*)&s[0][0];
    float* s2 = s1 + DIM1;
    if (tid < DIM1) s1[tid] = x1[n * DIM1 + tid];
    int t2 = tid - DIM1;
    if (t2 >= 0 && t2 < DIM2) s2[t2] = x2[n * DIM2 + t2];
    __syncthreads();
    for (int k8 = tid; k8 < U_LD / 8; k8 += 256) {
      union { ushort us[8]; uint4 v; } pk;
#pragma unroll
      for (int j = 0; j < 8; ++j) {
        int k = k8 * 8 + j;
        float val = 0.f;
        if (k < K_REAL) { int b = k / DIM2; int c = k - b * DIM2; val = s1[b] * s2[c]; }
        pk.us[j] = f2bf(val);
      }
      *(uint4*)&U[(size_t)n * U_LD + k8 * 8] = pk.v;
    }
  }
}

// ---- main GEMM: 128x128 tile, one a per block, 4 waves of 64x64 (m97 wave
//      shape: minimal LDS re-reads, 4-wave convoy), 16x16x32 MFMA,
//      counted-vmcnt double-buffer (R4 pipeline). 64KB LDS. ----
__global__ __launch_bounds__(256, 3) void gemm_kernel(const ushort* __restrict__ U,
                                                      const ushort* __restrict__ Wt,
                                                      const float* __restrict__ x0,
                                                      float* __restrict__ out) {
  // per buffer: A [128 rows][64 k] = 16KB (ushort 0..8191), B [128 o][64 k] = 16KB (8192..16383)
  __shared__ ushort lds[2][16384];   // 64 KB

  int tid = threadIdx.x;
  int lane = tid & 63;
  int w = tid >> 6;                  // 0..3
  int wr = w >> 1, wc = w & 1;       // wave tile: rows wr*64.., cols wc*64..

  // XCD-aware bijective swizzle: 528 blocks, 66 per XCD, a-major within XCD.
  int orig = (int)blockIdx.x;
  int logical = (orig & 7) * 66 + (orig >> 3);
  int a = logical >> 4;              // 0..32
  int m = logical & 15;              // 0..15
  int n0 = m * 128;

  int kblk = lane >> 4;              // 0..3
  int r15 = lane & 15;
  int swz = lane & 7;                // == row&7 for all fragment rows this lane touches

  f32x4 acc[4][4];
#pragma unroll
  for (int mi = 0; mi < 4; ++mi)
#pragma unroll
    for (int ni = 0; ni < 4; ++ni)
      acc[mi][ni] = (f32x4){0.f, 0.f, 0.f, 0.f};

  const ushort* WtA = Wt + (size_t)a * OO * U_LD;

  // --- per-thread staging: 8 chunks (4 A + 4 B), pointer-bumped +64 ushorts/step ---
  // chunk c in 0..1023: row = c>>3, slot = c&7; LDS dest linear c*16 bytes;
  // global source granule = slot ^ (row&7)  (involution, undone on read side)
  const ushort* pA[4]; const ushort* pB[4];
  int dA[4], dB[4];
#pragma unroll
  for (int i = 0; i < 4; ++i) {
    int c = i * 256 + tid;
    int row = c >> 3;
    int ss = (c & 7) ^ (row & 7);
    pA[i] = U + (size_t)(n0 + row) * U_LD + ss * 8;
    dA[i] = c * 8;
    pB[i] = WtA + (size_t)row * U_LD + ss * 8;
    dB[i] = 8192 + c * 8;
  }

  auto STAGE = [&](ushort* Lb) {
#pragma unroll
    for (int i = 0; i < 4; ++i) { GLOAD_LDS16(pA[i], Lb + dA[i]); pA[i] += 64; }
#pragma unroll
    for (int i = 0; i < 4; ++i) { GLOAD_LDS16(pB[i], Lb + dB[i]); pB[i] += 64; }
  };

  auto COMPUTE = [&](const ushort* Lb) {
    const char* base = (const char*)Lb;
#pragma unroll
    for (int ks = 0; ks < 2; ++ks) {
      bf16x8 af[4], bfr[4];
#pragma unroll
      for (int mi = 0; mi < 4; ++mi) {
        int off = (wr * 64 + mi * 16 + r15) * 128 + ((((ks * 4) + kblk) ^ swz) << 4);
        af[mi] = *(const bf16x8*)(base + off);
      }
#pragma unroll
      for (int ni = 0; ni < 4; ++ni) {
        int off = 16384 + (wc * 64 + ni * 16 + r15) * 128 + ((((ks * 4) + kblk) ^ swz) << 4);
        bfr[ni] = *(const bf16x8*)(base + off);
      }
      __builtin_amdgcn_s_setprio(1);
#pragma unroll
      for (int mi = 0; mi < 4; ++mi)
#pragma unroll
        for (int ni = 0; ni < 4; ++ni)
          acc[mi][ni] = __builtin_amdgcn_mfma_f32_16x16x32_bf16(af[mi], bfr[ni], acc[mi][ni], 0, 0, 0);
      __builtin_amdgcn_s_setprio(0);
    }
  };

  // prologue: tiles 0,1 in flight (16 loads/thread); wait tile 0 (keep 8 newest)
  STAGE(&lds[0][0]);
  STAGE(&lds[1][0]);
  asm volatile("s_waitcnt vmcnt(8)" ::: "memory");
  __builtin_amdgcn_s_barrier();

  // steady state: 34 tiles, 2x unroll for compile-time buffer index.
  for (int it = 0; it < 16; ++it) {
    COMPUTE(&lds[0][0]);
    __builtin_amdgcn_s_barrier();            // readers done with b0
    STAGE(&lds[0][0]);                       // tile 2it+2 -> b0 (16 in flight)
    asm volatile("s_waitcnt vmcnt(8)" ::: "memory");   // b1's tile landed
    __builtin_amdgcn_s_barrier();
    COMPUTE(&lds[1][0]);
    __builtin_amdgcn_s_barrier();
    STAGE(&lds[1][0]);                       // tile 2it+3 -> b1
    asm volatile("s_waitcnt vmcnt(8)" ::: "memory");   // b0's tile landed
    __builtin_amdgcn_s_barrier();
  }
  // tiles 32 (b0, landed) and 33 (b1, in flight)
  COMPUTE(&lds[0][0]);
  asm volatile("s_waitcnt vmcnt(0)" ::: "memory");
  __builtin_amdgcn_s_barrier();
  COMPUTE(&lds[1][0]);

  // epilogue: scale by x0[row, a], atomic-accumulate into out
  int jrow = (lane >> 4) * 4;
#pragma unroll
  for (int mi = 0; mi < 4; ++mi) {
#pragma unroll
    for (int j = 0; j < 4; ++j) {
      int row = n0 + wr * 64 + mi * 16 + jrow + j;
      float s = x0[(size_t)row * DIM0 + a];
#pragma unroll
      for (int ni = 0; ni < 4; ++ni) {
        int col = wc * 64 + ni * 16 + r15;
        atomicAdd(&out[(size_t)row * OO + col], acc[mi][ni][j] * s);
      }
    }
  }
}

// ---- bias + relu, in place on d_out ----
__global__ __launch_bounds__(256) void relu_kernel(float* __restrict__ out,
                                                   const float* __restrict__ bias) {
  int i = blockIdx.x * 256 + threadIdx.x;
  out[i] = fmaxf(out[i] + bias[i & (OO - 1)], 0.f);
}

extern "C" void kernel_launch(void* const* d_in, const int* in_sizes, int n_in,
                              void* d_out, int out_size, void* d_ws, size_t ws_size,
                              hipStream_t stream) {
  const float* x0   = (const float*)d_in[0];
  const float* x1   = (const float*)d_in[1];
  const float* x2   = (const float*)d_in[2];
  const float* W    = (const float*)d_in[3];
  const float* bias = (const float*)d_in[4];
  float* out = (float*)d_out;

  ushort* U  = (ushort*)d_ws;                                   // 2048*2176*2 = 8,912,896 B
  ushort* Wt = (ushort*)((char*)d_ws + (size_t)8912896);        // 33*128*2176*2 = 18,382,848 B

  hipMemsetAsync(d_out, 0, (size_t)NROW * OO * sizeof(float), stream);
  prep_kernel<<<34 * 33 + NROW, 256, 0, stream>>>(x1, x2, W, U, Wt);
  gemm_kernel<<<528, 256, 0, stream>>>(U, Wt, x0, out);
  relu_kernel<<<(NROW * OO) / 256, 256, 0, stream>>>(out, bias);
}